// Round 1
// baseline (12013.229 us; speedup 1.0000x reference)
//
#include <hip/hip_runtime.h>
#include <hip/hip_bf16.h>

// ---------------------------------------------------------------------------
// GCBlock: fused graph-transformer block (TransformerConv-style), f32.
//
//   P0 prep_wcomb : Wcomb[512][256] = stack(Wq,Wk,Wv,Wskip) @ W_n2m ; bcat[512]
//   P1 prep_wct   : WcT[64][128]    = (We @ W_edge)^T
//   G1 gemm_at    : QKVS[N][512]    = x @ Wcomb^T + bcat   (q|k|v|x_r per row)
//   EK edge_kernel: per (edge,head): e=ea@Wc^T slice, alpha=q[dst]·(k[src]+e),
//                   w=exp(alpha*scale); atomic out_un[dst]+= (v[src]+e)*w,
//                   asum[dst][h]+=w.  (max-free softmax; normalized later)
//   EP node_epilogue: out=out_un/asum; beta gate; writes g into QKVS q-slot
//   G2 gemm_at    : d_out[N][256] = g @ W_m2n^T
// ---------------------------------------------------------------------------

#define TE 64  // edges per tile in edge kernel

__global__ void prep_wcomb(const float* __restrict__ Wq, const float* __restrict__ bq,
                           const float* __restrict__ Wk, const float* __restrict__ bk,
                           const float* __restrict__ Wv, const float* __restrict__ bv,
                           const float* __restrict__ Wskip, const float* __restrict__ bskip,
                           const float* __restrict__ W_n2m,
                           float* __restrict__ wcomb, float* __restrict__ bcat) {
    int idx = blockIdx.x * 256 + threadIdx.x;   // 512*256 threads
    int oi = idx >> 8;       // 0..511
    int kk = idx & 255;      // 0..255
    int sel = oi >> 7, row = oi & 127;
    const float* Wsel; const float* bsel;
    if (sel == 0)      { Wsel = Wq;    bsel = bq;    }
    else if (sel == 1) { Wsel = Wk;    bsel = bk;    }
    else if (sel == 2) { Wsel = Wv;    bsel = bv;    }
    else               { Wsel = Wskip; bsel = bskip; }
    float s = 0.f;
    for (int t = 0; t < 128; ++t)
        s = fmaf(Wsel[row * 128 + t], W_n2m[t * 256 + kk], s);
    wcomb[oi * 256 + kk] = s;
    if (kk == 0) bcat[oi] = bsel[row];
}

__global__ void prep_wct(const float* __restrict__ We, const float* __restrict__ W_edge,
                         float* __restrict__ wct) {
    int idx = blockIdx.x * 256 + threadIdx.x;   // 64*128 threads
    int r = idx >> 7;
    int j = idx & 127;
    float s = 0.f;
    for (int k = 0; k < 64; ++k)
        s = fmaf(We[j * 64 + k], W_edge[k * 64 + r], s);
    wct[r * 128 + j] = s;   // WcT[r][j] = Wc[j][r]
}

// C[m][n] = bias[n] + sum_k A[m*lda+k]*W[n*ldw+k]
// BM=BN=128, KC=32, 256 threads, 8x8/thread (split 4+4). K%32==0, Nout%128==0.
__global__ __launch_bounds__(256)
void gemm_at(const float* __restrict__ A, int lda,
             const float* __restrict__ W, int ldw,
             const float* __restrict__ bias,
             float* __restrict__ C, int ldc,
             int M, int K) {
    __shared__ float As[32 * 132];
    __shared__ float Bs[32 * 132];
    const int t  = threadIdx.x;
    const int tx = t & 15, ty = t >> 4;
    const int m0 = blockIdx.x * 128;
    const int n0 = blockIdx.y * 128;

    float acc[8][8];
    #pragma unroll
    for (int i = 0; i < 8; ++i)
        #pragma unroll
        for (int j = 0; j < 8; ++j) acc[i][j] = 0.f;

    for (int k0 = 0; k0 < K; k0 += 32) {
        #pragma unroll
        for (int i = 0; i < 4; ++i) {
            int f  = t + i * 256;
            int m  = f >> 3;
            int kc = (f & 7) << 2;
            float4 v = make_float4(0.f, 0.f, 0.f, 0.f);
            if (m0 + m < M)
                v = *(const float4*)(A + (size_t)(m0 + m) * lda + k0 + kc);
            As[(kc + 0) * 132 + m] = v.x;
            As[(kc + 1) * 132 + m] = v.y;
            As[(kc + 2) * 132 + m] = v.z;
            As[(kc + 3) * 132 + m] = v.w;
        }
        #pragma unroll
        for (int i = 0; i < 4; ++i) {
            int f  = t + i * 256;
            int n  = f >> 3;
            int kc = (f & 7) << 2;
            float4 v = *(const float4*)(W + (size_t)(n0 + n) * ldw + k0 + kc);
            Bs[(kc + 0) * 132 + n] = v.x;
            Bs[(kc + 1) * 132 + n] = v.y;
            Bs[(kc + 2) * 132 + n] = v.z;
            Bs[(kc + 3) * 132 + n] = v.w;
        }
        __syncthreads();

        const float4* As4 = (const float4*)As;
        const float4* Bs4 = (const float4*)Bs;
        #pragma unroll
        for (int kk = 0; kk < 32; ++kk) {
            float4 a0 = As4[kk * 33 + ty];
            float4 a1 = As4[kk * 33 + 16 + ty];
            float4 b0 = Bs4[kk * 33 + tx];
            float4 b1 = Bs4[kk * 33 + 16 + tx];
            float ar[8] = {a0.x, a0.y, a0.z, a0.w, a1.x, a1.y, a1.z, a1.w};
            float br[8] = {b0.x, b0.y, b0.z, b0.w, b1.x, b1.y, b1.z, b1.w};
            #pragma unroll
            for (int i = 0; i < 8; ++i)
                #pragma unroll
                for (int j = 0; j < 8; ++j)
                    acc[i][j] = fmaf(ar[i], br[j], acc[i][j]);
        }
        __syncthreads();
    }

    float4 bc0 = make_float4(0.f, 0.f, 0.f, 0.f);
    float4 bc1 = make_float4(0.f, 0.f, 0.f, 0.f);
    if (bias) {
        bc0 = *(const float4*)(bias + n0 + tx * 4);
        bc1 = *(const float4*)(bias + n0 + 64 + tx * 4);
    }
    #pragma unroll
    for (int i = 0; i < 8; ++i) {
        int row = m0 + ((i < 4) ? (ty * 4 + i) : (64 + ty * 4 + (i - 4)));
        if (row < M) {
            float4 c0 = make_float4(acc[i][0] + bc0.x, acc[i][1] + bc0.y,
                                    acc[i][2] + bc0.z, acc[i][3] + bc0.w);
            float4 c1 = make_float4(acc[i][4] + bc1.x, acc[i][5] + bc1.y,
                                    acc[i][6] + bc1.z, acc[i][7] + bc1.w);
            *(float4*)(C + (size_t)row * ldc + n0 + tx * 4)      = c0;
            *(float4*)(C + (size_t)row * ldc + n0 + 64 + tx * 4) = c1;
        }
    }
}

// 256 threads = 64 edges x 4 heads per tile; grid-stride over tiles.
__global__ __launch_bounds__(256)
void edge_kernel(const float* __restrict__ ea, const int* __restrict__ ei,
                 const float* __restrict__ wct_g,   // [64][128]
                 const float* __restrict__ qkvs,    // [N][512] q|k|v|x_r
                 float* __restrict__ out_un,        // [N][128] zeroed
                 float* __restrict__ asum,          // [N][4]   zeroed
                 int E, int ntiles) {
    __shared__ float wct[64 * 144];
    __shared__ float eas[TE * 68];
    const int t = threadIdx.x;

    // stage WcT once: wct[r*144 + h*36 + c] = WcT_g[r][h*32+c]
    #pragma unroll
    for (int i = 0; i < 8; ++i) {
        int f = t + i * 256;
        int r = f >> 5;
        int u = f & 31;
        float4 v = *(const float4*)(wct_g + (size_t)f * 4);
        int h = u >> 3, c = (u & 7) << 2;
        *(float4*)(wct + r * 144 + h * 36 + c) = v;
    }

    const int le = t >> 2;
    const int h  = t & 3;

    for (int tile = blockIdx.x; tile < ntiles; tile += gridDim.x) {
        __syncthreads();
        int e0 = tile * TE;
        #pragma unroll
        for (int i = 0; i < 4; ++i) {
            int f    = t + i * 256;
            int edge = f >> 4;
            int r0   = (f & 15) << 2;
            float4 v = make_float4(0.f, 0.f, 0.f, 0.f);
            if (e0 + edge < E)
                v = *(const float4*)(ea + (size_t)(e0 + edge) * 64 + r0);
            *(float4*)(eas + edge * 68 + r0) = v;
        }
        __syncthreads();

        int e = e0 + le;
        if (e < E) {
            int src = ei[e];
            int dst = ei[(size_t)E + e];

            float acc[32];
            #pragma unroll
            for (int i = 0; i < 32; ++i) acc[i] = 0.f;
            const float* earow = eas + le * 68;
            #pragma unroll 2
            for (int r = 0; r < 64; ++r) {
                float a = earow[r];
                const float4* wr = (const float4*)(wct + r * 144 + h * 36);
                #pragma unroll
                for (int i = 0; i < 8; ++i) {
                    float4 w4 = wr[i];
                    acc[4 * i + 0] = fmaf(a, w4.x, acc[4 * i + 0]);
                    acc[4 * i + 1] = fmaf(a, w4.y, acc[4 * i + 1]);
                    acc[4 * i + 2] = fmaf(a, w4.z, acc[4 * i + 2]);
                    acc[4 * i + 3] = fmaf(a, w4.w, acc[4 * i + 3]);
                }
            }

            const float* qrow = qkvs + (size_t)dst * 512 + h * 32;
            const float* krow = qkvs + (size_t)src * 512 + 128 + h * 32;
            float alpha = 0.f;
            #pragma unroll
            for (int i = 0; i < 8; ++i) {
                float4 q4 = *(const float4*)(qrow + 4 * i);
                float4 k4 = *(const float4*)(krow + 4 * i);
                alpha = fmaf(q4.x, k4.x + acc[4 * i + 0], alpha);
                alpha = fmaf(q4.y, k4.y + acc[4 * i + 1], alpha);
                alpha = fmaf(q4.z, k4.z + acc[4 * i + 2], alpha);
                alpha = fmaf(q4.w, k4.w + acc[4 * i + 3], alpha);
            }
            float w = __expf(alpha * 0.17677669529663687f);  // 1/sqrt(32)

            const float* vrow = qkvs + (size_t)src * 512 + 256 + h * 32;
            float* orow = out_un + (size_t)dst * 128 + h * 32;
            #pragma unroll
            for (int i = 0; i < 8; ++i) {
                float4 v4 = *(const float4*)(vrow + 4 * i);
                atomicAdd(orow + 4 * i + 0, (v4.x + acc[4 * i + 0]) * w);
                atomicAdd(orow + 4 * i + 1, (v4.y + acc[4 * i + 1]) * w);
                atomicAdd(orow + 4 * i + 2, (v4.z + acc[4 * i + 2]) * w);
                atomicAdd(orow + 4 * i + 3, (v4.w + acc[4 * i + 3]) * w);
            }
            atomicAdd(asum + (size_t)dst * 4 + h, w);
        }
    }
}

__global__ __launch_bounds__(256)
void node_epilogue(const float* __restrict__ out_un, const float* __restrict__ asum,
                   float* __restrict__ qkvs,
                   const float* __restrict__ wbeta,
                   int N) {
    int lane = threadIdx.x & 63;
    int wid  = threadIdx.x >> 6;
    int n = blockIdx.x * 4 + wid;
    if (n >= N) return;
    int c = lane * 2;
    float2 o2 = *(const float2*)(out_un + (size_t)n * 128 + c);
    float a   = asum[(size_t)n * 4 + (c >> 5)];
    float inv = 1.0f / (a + 1e-16f);
    float ox = o2.x * inv, oy = o2.y * inv;
    float2 xr = *(const float2*)(qkvs + (size_t)n * 512 + 384 + c);
    float2 w0 = *(const float2*)(wbeta + c);
    float2 w1 = *(const float2*)(wbeta + 128 + c);
    float2 w2 = *(const float2*)(wbeta + 256 + c);
    float p = w0.x * ox + w0.y * oy
            + w1.x * xr.x + w1.y * xr.y
            + w2.x * (ox - xr.x) + w2.y * (oy - xr.y);
    #pragma unroll
    for (int off = 1; off < 64; off <<= 1)
        p += __shfl_xor(p, off);
    float beta = 1.0f / (1.0f + __expf(-p));
    float gx = beta * xr.x + (1.0f - beta) * ox;
    float gy = beta * xr.y + (1.0f - beta) * oy;
    *(float2*)(qkvs + (size_t)n * 512 + c) = make_float2(gx, gy);
}

extern "C" void kernel_launch(void* const* d_in, const int* in_sizes, int n_in,
                              void* d_out, int out_size, void* d_ws, size_t ws_size,
                              hipStream_t stream) {
    const float* x         = (const float*)d_in[0];
    const float* edge_attr = (const float*)d_in[1];
    const int*   ei        = (const int*)d_in[2];
    const float* W_edge    = (const float*)d_in[3];
    const float* W_n2m     = (const float*)d_in[4];
    const float* Wq        = (const float*)d_in[5];
    const float* bq        = (const float*)d_in[6];
    const float* Wk        = (const float*)d_in[7];
    const float* bk        = (const float*)d_in[8];
    const float* Wv        = (const float*)d_in[9];
    const float* bv        = (const float*)d_in[10];
    const float* We        = (const float*)d_in[11];
    const float* Wskip     = (const float*)d_in[12];
    const float* bskip     = (const float*)d_in[13];
    const float* Wbeta     = (const float*)d_in[14];
    const float* W_m2n     = (const float*)d_in[15];

    const int N = in_sizes[0] / 256;
    const int E = in_sizes[1] / 64;

    float* out    = (float*)d_out;
    float* out_un = out;                       // reuse d_out front as [N][128]
    float* qkvs   = (float*)d_ws;              // [N][512]
    float* asum   = qkvs + (size_t)N * 512;    // [N][4]
    float* wcomb  = asum + (size_t)N * 4;      // [512][256]
    float* bcat   = wcomb + 512 * 256;         // [512]
    float* wct    = bcat + 512;                // [64][128]

    hipMemsetAsync(out_un, 0, (size_t)N * 128 * sizeof(float), stream);
    hipMemsetAsync(asum, 0, (size_t)N * 4 * sizeof(float), stream);

    prep_wcomb<<<512, 256, 0, stream>>>(Wq, bq, Wk, bk, Wv, bv, Wskip, bskip,
                                        W_n2m, wcomb, bcat);
    prep_wct<<<32, 256, 0, stream>>>(We, W_edge, wct);

    gemm_at<<<dim3((N + 127) / 128, 4), 256, 0, stream>>>(
        x, 256, wcomb, 256, bcat, qkvs, 512, N, 256);

    int ntiles = (E + TE - 1) / TE;
    int eblocks = ntiles < 2048 ? ntiles : 2048;
    edge_kernel<<<eblocks, 256, 0, stream>>>(edge_attr, ei, wct, qkvs,
                                             out_un, asum, E, ntiles);

    node_epilogue<<<(N + 3) / 4, 256, 0, stream>>>(out_un, asum, qkvs, Wbeta, N);

    gemm_at<<<dim3((N + 127) / 128, 2), 256, 0, stream>>>(
        qkvs, 512, W_m2n, 128, nullptr, out, 256, N, 128);
}

// Round 4
// 2241.378 us; speedup vs baseline: 5.3598x; 5.3598x over previous
//
#include <hip/hip_runtime.h>
#include <hip/hip_bf16.h>

// ---------------------------------------------------------------------------
// GCBlock fused graph-transformer block, f32, CSR-gather edition (no f32 atomics).
//
//   P0 prep_wcomb : Wcomb[512][256] = stack(Wq,Wk,Wv,Wskip) @ W_n2m ; bcat[512]
//   P1 prep_wct   : WcT[64][128]    = (We @ W_edge)^T
//   CSR build     : hist -> 3-kernel scan -> scatter (int atomics only)
//   G1 gemm_at    : QKVS[N][512] = x @ Wcomb^T + bcat   (q|k|v|x_r per row)
//   GA gather     : per dst (1 wave): for each in-edge recompute e, logit,
//                   w=exp(alpha*scale); accumulate in regs; normalize; beta
//                   gate; write g into QKVS cols 0..127. No atomics.
//   G2 gemm_at    : d_out[N][256] = g @ W_m2n^T
//
// Scratch layout: int/CSR arrays live in d_out (dead before G2 overwrites it);
// d_ws holds qkvs + folded weights (~205 MB, within round-1-proven budget).
// ---------------------------------------------------------------------------

#define SCAN_BLK 2048  // elements per scan block (256 thr x 8)

__global__ void prep_wcomb(const float* __restrict__ Wq, const float* __restrict__ bq,
                           const float* __restrict__ Wk, const float* __restrict__ bk,
                           const float* __restrict__ Wv, const float* __restrict__ bv,
                           const float* __restrict__ Wskip, const float* __restrict__ bskip,
                           const float* __restrict__ W_n2m,
                           float* __restrict__ wcomb, float* __restrict__ bcat) {
    int idx = blockIdx.x * 256 + threadIdx.x;   // 512*256 threads
    int oi = idx >> 8;
    int kk = idx & 255;
    int sel = oi >> 7, row = oi & 127;
    const float* Wsel; const float* bsel;
    if (sel == 0)      { Wsel = Wq;    bsel = bq;    }
    else if (sel == 1) { Wsel = Wk;    bsel = bk;    }
    else if (sel == 2) { Wsel = Wv;    bsel = bv;    }
    else               { Wsel = Wskip; bsel = bskip; }
    float s = 0.f;
    for (int t = 0; t < 128; ++t)
        s = fmaf(Wsel[row * 128 + t], W_n2m[t * 256 + kk], s);
    wcomb[oi * 256 + kk] = s;
    if (kk == 0) bcat[oi] = bsel[row];
}

__global__ void prep_wct(const float* __restrict__ We, const float* __restrict__ W_edge,
                         float* __restrict__ wct) {
    int idx = blockIdx.x * 256 + threadIdx.x;   // 64*128 threads
    int r = idx >> 7;
    int j = idx & 127;
    float s = 0.f;
    for (int k = 0; k < 64; ++k)
        s = fmaf(We[j * 64 + k], W_edge[k * 64 + r], s);
    wct[r * 128 + j] = s;   // WcT[r][j] = Wc[j][r]
}

// ---------------- CSR build ----------------
__global__ void k_hist(const int* __restrict__ ei, int* __restrict__ hist, int E) {
    int e = blockIdx.x * 256 + threadIdx.x;
    if (e < E) atomicAdd(&hist[ei[E + e]], 1);
}

__global__ __launch_bounds__(256)
void scan_blocks(const int* __restrict__ hist, int* __restrict__ excl,
                 int* __restrict__ bsums, int N) {
    __shared__ int ts[256];
    int t = threadIdx.x;
    int base = blockIdx.x * SCAN_BLK + t * 8;
    int v[8];
    int s = 0;
    #pragma unroll
    for (int i = 0; i < 8; ++i) {
        int idx = base + i;
        int h = (idx < N) ? hist[idx] : 0;
        v[i] = s;
        s += h;
    }
    ts[t] = s;
    __syncthreads();
    for (int off = 1; off < 256; off <<= 1) {
        int x = ts[t];
        if (t >= off) x += ts[t - off];
        __syncthreads();
        ts[t] = x;
        __syncthreads();
    }
    int incl = ts[t];
    int excl_t = incl - s;
    #pragma unroll
    for (int i = 0; i < 8; ++i) {
        int idx = base + i;
        if (idx < N) excl[idx] = v[i] + excl_t;
    }
    if (t == 255) bsums[blockIdx.x] = incl;
}

__global__ void scan_tops(int* __restrict__ bsums, int nblk) {
    if (threadIdx.x == 0 && blockIdx.x == 0) {
        int run = 0;
        for (int i = 0; i < nblk; ++i) {
            int b = bsums[i];
            bsums[i] = run;
            run += b;
        }
    }
}

__global__ void scan_add(int* __restrict__ row_start, int* __restrict__ cursor,
                         const int* __restrict__ bsums, int N, int E) {
    int i = blockIdx.x * 256 + threadIdx.x;
    if (i < N) {
        int v = row_start[i] + bsums[i / SCAN_BLK];
        row_start[i] = v;
        cursor[i] = v;
    }
    if (i == 0) row_start[N] = E;
}

__global__ void k_scatter(const int* __restrict__ ei, int* __restrict__ cursor,
                          int* __restrict__ csr, int E) {
    int e = blockIdx.x * 256 + threadIdx.x;
    if (e < E) {
        int d = ei[E + e];
        int p = atomicAdd(&cursor[d], 1);
        csr[p] = e;
    }
}

// ---------------- f32 GEMM: C = A @ W^T (+bias) ----------------
// BM=BN=128, KC=32, 256 threads, 8x8/thread. K%32==0, Nout%128==0, M guarded.
__global__ __launch_bounds__(256)
void gemm_at(const float* __restrict__ A, int lda,
             const float* __restrict__ W, int ldw,
             const float* __restrict__ bias,
             float* __restrict__ C, int ldc,
             int M, int K) {
    __shared__ float As[32 * 132];
    __shared__ float Bs[32 * 132];
    const int t  = threadIdx.x;
    const int tx = t & 15, ty = t >> 4;
    const int m0 = blockIdx.x * 128;
    const int n0 = blockIdx.y * 128;

    float acc[8][8];
    #pragma unroll
    for (int i = 0; i < 8; ++i)
        #pragma unroll
        for (int j = 0; j < 8; ++j) acc[i][j] = 0.f;

    for (int k0 = 0; k0 < K; k0 += 32) {
        #pragma unroll
        for (int i = 0; i < 4; ++i) {
            int f  = t + i * 256;
            int m  = f >> 3;
            int kc = (f & 7) << 2;
            float4 v = make_float4(0.f, 0.f, 0.f, 0.f);
            if (m0 + m < M)
                v = *(const float4*)(A + (size_t)(m0 + m) * lda + k0 + kc);
            As[(kc + 0) * 132 + m] = v.x;
            As[(kc + 1) * 132 + m] = v.y;
            As[(kc + 2) * 132 + m] = v.z;
            As[(kc + 3) * 132 + m] = v.w;
        }
        #pragma unroll
        for (int i = 0; i < 4; ++i) {
            int f  = t + i * 256;
            int n  = f >> 3;
            int kc = (f & 7) << 2;
            float4 v = *(const float4*)(W + (size_t)(n0 + n) * ldw + k0 + kc);
            Bs[(kc + 0) * 132 + n] = v.x;
            Bs[(kc + 1) * 132 + n] = v.y;
            Bs[(kc + 2) * 132 + n] = v.z;
            Bs[(kc + 3) * 132 + n] = v.w;
        }
        __syncthreads();

        const float4* As4 = (const float4*)As;
        const float4* Bs4 = (const float4*)Bs;
        #pragma unroll
        for (int kk = 0; kk < 32; ++kk) {
            float4 a0 = As4[kk * 33 + ty];
            float4 a1 = As4[kk * 33 + 16 + ty];
            float4 b0 = Bs4[kk * 33 + tx];
            float4 b1 = Bs4[kk * 33 + 16 + tx];
            float ar[8] = {a0.x, a0.y, a0.z, a0.w, a1.x, a1.y, a1.z, a1.w};
            float br[8] = {b0.x, b0.y, b0.z, b0.w, b1.x, b1.y, b1.z, b1.w};
            #pragma unroll
            for (int i = 0; i < 8; ++i)
                #pragma unroll
                for (int j = 0; j < 8; ++j)
                    acc[i][j] = fmaf(ar[i], br[j], acc[i][j]);
        }
        __syncthreads();
    }

    float4 bc0 = make_float4(0.f, 0.f, 0.f, 0.f);
    float4 bc1 = make_float4(0.f, 0.f, 0.f, 0.f);
    if (bias) {
        bc0 = *(const float4*)(bias + n0 + tx * 4);
        bc1 = *(const float4*)(bias + n0 + 64 + tx * 4);
    }
    #pragma unroll
    for (int i = 0; i < 8; ++i) {
        int row = m0 + ((i < 4) ? (ty * 4 + i) : (64 + ty * 4 + (i - 4)));
        if (row < M) {
            float4 c0 = make_float4(acc[i][0] + bc0.x, acc[i][1] + bc0.y,
                                    acc[i][2] + bc0.z, acc[i][3] + bc0.w);
            float4 c1 = make_float4(acc[i][4] + bc1.x, acc[i][5] + bc1.y,
                                    acc[i][6] + bc1.z, acc[i][7] + bc1.w);
            *(float4*)(C + (size_t)row * ldc + n0 + tx * 4)      = c0;
            *(float4*)(C + (size_t)row * ldc + n0 + 64 + tx * 4) = c1;
        }
    }
}

// ---------------- gather: one wave per dst node ----------------
// lane owns output channels {lane, lane+64}. wct in LDS (2-way = free reads).
// ea row broadcast from registers via v_readlane. Processes edges in pairs.
__global__ __launch_bounds__(256)
void gather_kernel(const float* __restrict__ ea, const int* __restrict__ ei,
                   const float* __restrict__ wct_g,     // [64][128]
                   const int* __restrict__ row_start,   // [N+1]
                   const int* __restrict__ csr,         // [E]
                   float* __restrict__ qkvs,            // [N][512] q|k|v|x_r
                   const float* __restrict__ wbeta,     // [384]
                   int N, int E) {
    __shared__ float wct[64 * 128];
    const int t = threadIdx.x;
    #pragma unroll
    for (int i = 0; i < 8; ++i) {
        int f = t + i * 256;     // float4 idx 0..2047
        *(float4*)(wct + (size_t)f * 4) = *(const float4*)(wct_g + (size_t)f * 4);
    }
    __syncthreads();

    const int lane = t & 63;
    const int dst  = blockIdx.x * 4 + (t >> 6);
    if (dst >= N) return;

    const int rs = row_start[dst];
    const int re = row_start[dst + 1];

    const float q_lo = qkvs[(size_t)dst * 512 + lane];
    const float q_hi = qkvs[(size_t)dst * 512 + 64 + lane];
    const float scale = 0.17677669529663687f;  // 1/sqrt(32)

    float o_lo = 0.f, o_hi = 0.f, ws_lo = 0.f, ws_hi = 0.f;

    for (int j = rs; j < re; j += 2) {
        const int  e0   = csr[j];
        const bool has1 = (j + 1 < re);
        const int  e1   = has1 ? csr[j + 1] : e0;
        const int  s0 = ei[e0], s1 = ei[e1];

        const int avi0 = __float_as_int(ea[(size_t)e0 * 64 + lane]);
        const int avi1 = __float_as_int(ea[(size_t)e1 * 64 + lane]);

        const float* r0 = qkvs + (size_t)s0 * 512;
        const float* r1 = qkvs + (size_t)s1 * 512;
        const float k0l = r0[128 + lane], k0h = r0[192 + lane];
        const float v0l = r0[256 + lane], v0h = r0[320 + lane];
        const float k1l = r1[128 + lane], k1h = r1[192 + lane];
        const float v1l = r1[256 + lane], v1h = r1[320 + lane];

        float e0l = 0.f, e0h = 0.f, e1l = 0.f, e1h = 0.f;
        #pragma unroll
        for (int r = 0; r < 64; ++r) {
            const float wl = wct[r * 128 + lane];
            const float wh = wct[r * 128 + 64 + lane];
            const float a0 = __int_as_float(__builtin_amdgcn_readlane(avi0, r));
            const float a1 = __int_as_float(__builtin_amdgcn_readlane(avi1, r));
            e0l = fmaf(a0, wl, e0l); e0h = fmaf(a0, wh, e0h);
            e1l = fmaf(a1, wl, e1l); e1h = fmaf(a1, wh, e1h);
        }

        // attention logits: per-lane partials, reduce within 32-lane groups
        float p0l = q_lo * (k0l + e0l), p0h = q_hi * (k0h + e0h);
        float p1l = q_lo * (k1l + e1l), p1h = q_hi * (k1h + e1h);
        #pragma unroll
        for (int off = 1; off < 32; off <<= 1) {
            p0l += __shfl_xor(p0l, off); p0h += __shfl_xor(p0h, off);
            p1l += __shfl_xor(p1l, off); p1h += __shfl_xor(p1h, off);
        }
        // max-free softmax weights (logits are O(1); exp safe in f32)
        const float w0l = __expf(p0l * scale);
        const float w0h = __expf(p0h * scale);
        const float w1l = has1 ? __expf(p1l * scale) : 0.f;
        const float w1h = has1 ? __expf(p1h * scale) : 0.f;

        o_lo = fmaf(w0l, v0l + e0l, o_lo); o_hi = fmaf(w0h, v0h + e0h, o_hi);
        o_lo = fmaf(w1l, v1l + e1l, o_lo); o_hi = fmaf(w1h, v1h + e1h, o_hi);
        ws_lo += w0l + w1l;
        ws_hi += w0h + w1h;
    }

    o_lo *= 1.f / (ws_lo + 1e-16f);
    o_hi *= 1.f / (ws_hi + 1e-16f);

    // beta-gated skip
    const float xr_lo = qkvs[(size_t)dst * 512 + 384 + lane];
    const float xr_hi = qkvs[(size_t)dst * 512 + 448 + lane];
    float p = wbeta[lane]       * o_lo + wbeta[64 + lane]  * o_hi
            + wbeta[128 + lane] * xr_lo + wbeta[192 + lane] * xr_hi
            + wbeta[256 + lane] * (o_lo - xr_lo) + wbeta[320 + lane] * (o_hi - xr_hi);
    #pragma unroll
    for (int off = 1; off < 64; off <<= 1) p += __shfl_xor(p, off);
    const float beta = 1.f / (1.f + __expf(-p));
    const float g_lo = beta * xr_lo + (1.f - beta) * o_lo;
    const float g_hi = beta * xr_hi + (1.f - beta) * o_hi;
    qkvs[(size_t)dst * 512 + lane]      = g_lo;
    qkvs[(size_t)dst * 512 + 64 + lane] = g_hi;
}

// ---------------- launcher ----------------
extern "C" void kernel_launch(void* const* d_in, const int* in_sizes, int n_in,
                              void* d_out, int out_size, void* d_ws, size_t ws_size,
                              hipStream_t stream) {
    const float* x         = (const float*)d_in[0];
    const float* edge_attr = (const float*)d_in[1];
    const int*   ei        = (const int*)d_in[2];
    const float* W_edge    = (const float*)d_in[3];
    const float* W_n2m     = (const float*)d_in[4];
    const float* Wq        = (const float*)d_in[5];
    const float* bq        = (const float*)d_in[6];
    const float* Wk        = (const float*)d_in[7];
    const float* bk        = (const float*)d_in[8];
    const float* Wv        = (const float*)d_in[9];
    const float* bv        = (const float*)d_in[10];
    const float* We        = (const float*)d_in[11];
    const float* Wskip     = (const float*)d_in[12];
    const float* bskip     = (const float*)d_in[13];
    const float* Wbeta     = (const float*)d_in[14];
    const float* W_m2n     = (const float*)d_in[15];

    const int N = in_sizes[0] / 256;
    const int E = in_sizes[1] / 64;

    float* out   = (float*)d_out;
    // d_ws: qkvs + folded weights (~205.4 MB)
    float* qkvs  = (float*)d_ws;                       // [N][512]
    float* wcomb = qkvs + (size_t)N * 512;             // [512][256]
    float* bcat  = wcomb + 512 * 256;                  // [512]
    float* wct   = bcat + 512;                         // [64][128]
    // d_out front doubles as int scratch; fully overwritten by G2 afterwards.
    int* hist      = (int*)d_out;                      // [N]
    int* row_start = hist + N;                         // [N+1]
    int* cursor    = row_start + N + 1;                // [N]
    int* bsums     = cursor + N;                       // [64]
    int* csr       = bsums + 64;                       // [E]  (total ~7.6 MB << 102 MB)

    const int nblk = (N + SCAN_BLK - 1) / SCAN_BLK;

    hipMemsetAsync(hist, 0, (size_t)N * sizeof(int), stream);

    prep_wcomb<<<512, 256, 0, stream>>>(Wq, bq, Wk, bk, Wv, bv, Wskip, bskip,
                                        W_n2m, wcomb, bcat);
    prep_wct<<<32, 256, 0, stream>>>(We, W_edge, wct);

    // CSR build (int atomics only)
    k_hist<<<(E + 255) / 256, 256, 0, stream>>>(ei, hist, E);
    scan_blocks<<<nblk, 256, 0, stream>>>(hist, row_start, bsums, N);
    scan_tops<<<1, 64, 0, stream>>>(bsums, nblk);
    scan_add<<<(N + 255) / 256, 256, 0, stream>>>(row_start, cursor, bsums, N, E);
    k_scatter<<<(E + 255) / 256, 256, 0, stream>>>(ei, cursor, csr, E);

    // QKVS = x @ Wcomb^T + bcat : M=N, K=256, Nout=512
    gemm_at<<<dim3((N + 127) / 128, 4), 256, 0, stream>>>(
        x, 256, wcomb, 256, bcat, qkvs, 512, N, 256);

    // per-dst gather (writes g into qkvs cols 0..127)
    gather_kernel<<<(N + 3) / 4, 256, 0, stream>>>(
        edge_attr, ei, wct, row_start, csr, qkvs, Wbeta, N, E);

    // d_out = g @ W_m2n^T : M=N, K=128, Nout=256
    gemm_at<<<dim3((N + 127) / 128, 2), 256, 0, stream>>>(
        qkvs, 512, W_m2n, 128, nullptr, out, 256, N, 128);
}